// Round 8
// baseline (234.038 us; speedup 1.0000x reference)
//
#include <hip/hip_runtime.h>
#include <math.h>

#pragma clang fp contract(off)

#define NN 2
#define VV 2048
#define FF 2048
#define HH 384
#define WW 384
#define TH 1024
#define TW 1024
#define EPSD 1e-08
#define SLICES 16
#define FPS (FF / SLICES)                          // 128 faces per slice
#define SETUP_BLOCKS ((NN * FF + 255) / 256)       // 16
#define CLEAR_BLOCKS ((NN * HH * WW + 255) / 256)  // 1152

// Separately-rounded fp32 multiply (blocks backend FMA fusion).
__device__ __forceinline__ float mulr(float a, float b) {
    float p = a * b;
    asm("" : "+v"(p));
    return p;
}

// dface: 16 doubles/face: [0..8] G (b_i affine), [9..11] Zx,Zy,Zc,
//   [12] ubkey (u64 bit-pattern: (bits(max rz)&~0x7FF)|2047 — upper bound
//   on any inside-pixel key of this face), [13..15] pad
// uvface: 8 doubles/face (render only)
// cull: float4 x4 (bbox + sign-adjusted raw edge coeffs; !ok → C=-3e30)
// perm: ushort[NN][SLICES][FPS] — faces in global front-to-back order,
//   dealt round-robin to slices (written by `order`)

__global__ __launch_bounds__(256) void setup_and_clear(
    const float* __restrict__ v, const float* __restrict__ campos,
    const float* __restrict__ camrot, const float* __restrict__ focal,
    const float* __restrict__ princpt, const int* __restrict__ vi,
    const float* __restrict__ vt, const int* __restrict__ vti,
    double* __restrict__ dface, double* __restrict__ uvface,
    float4* __restrict__ cull, unsigned long long* __restrict__ keybuf)
{
#pragma clang fp contract(off)
    if (blockIdx.x >= SETUP_BLOCKS) {
        int idx = (blockIdx.x - SETUP_BLOCKS) * 256 + threadIdx.x;
        if (idx < NN * HH * WW) keybuf[idx] = 0ull;
        return;
    }
    int t = blockIdx.x * blockDim.x + threadIdx.x;
    if (t >= NN * FF) return;
    int n = t / FF, f = t % FF;
    const float* cr = camrot + n * 9;
    const float* cp = campos + n * 3;
    const float* fo = focal + n * 4;
    const float* pp = princpt + n * 2;
    float X[3], Y[3], Z[3];
    for (int k = 0; k < 3; ++k) {
        int vid = vi[f * 3 + k];
        const float* vp = v + ((size_t)n * VV + vid) * 3;
        float d0 = vp[0] - cp[0];
        float d1 = vp[1] - cp[1];
        float d2 = vp[2] - cp[2];
        float c0 = (mulr(cr[0], d0) + mulr(cr[1], d1)) + mulr(cr[2], d2);
        float c1 = (mulr(cr[3], d0) + mulr(cr[4], d1)) + mulr(cr[5], d2);
        float c2 = (mulr(cr[6], d0) + mulr(cr[7], d1)) + mulr(cr[8], d2);
        float u = c0 / c2;
        float w = c1 / c2;
        X[k] = (mulr(fo[0], u) + mulr(fo[1], w)) + pp[0];
        Y[k] = (mulr(fo[2], u) + mulr(fo[3], w)) + pp[1];
        Z[k] = c2;
    }
    float area = mulr(X[1] - X[0], Y[2] - Y[0]) - mulr(Y[1] - Y[0], X[2] - X[0]);
    bool ok = fabsf(area) > 1e-9f;
    float inv = ok ? (1.0f / area) : __builtin_nanf("");
    float e0x = X[2] - X[1], e0y = Y[2] - Y[1];
    float e1x = X[0] - X[2], e1y = Y[0] - Y[2];
    float e2x = X[1] - X[0], e2y = Y[1] - Y[0];
    double invd = (double)inv;
    double e0xd = (double)e0x, e0yd = (double)e0y;
    double e1xd = (double)e1x, e1yd = (double)e1y;
    double e2xd = (double)e2x, e2yd = (double)e2y;
    double x0d = (double)X[0], y0d = (double)Y[0];
    double x1d = (double)X[1], y1d = (double)Y[1];
    double x2d = (double)X[2], y2d = (double)Y[2];
    double rz0 = 1.0 / (double)Z[0];
    double rz1 = 1.0 / (double)Z[1];
    double rz2 = 1.0 / (double)Z[2];
    double Gx0 = -e0yd * invd, Gy0 = e0xd * invd, Gc0 = (e0yd * x1d - e0xd * y1d) * invd;
    double Gx1 = -e1yd * invd, Gy1 = e1xd * invd, Gc1 = (e1yd * x2d - e1xd * y2d) * invd;
    double Gx2 = -e2yd * invd, Gy2 = e2xd * invd, Gc2 = (e2yd * x0d - e2xd * y0d) * invd;
    double Zx = Gx0 * rz0 + Gx1 * rz1 + Gx2 * rz2;
    double Zy = Gy0 * rz0 + Gy1 * rz1 + Gy2 * rz2;
    double Zc = Gc0 * rz0 + Gc1 * rz1 + Gc2 * rz2;
    double* dd = dface + (size_t)t * 16;
    dd[0] = Gx0; dd[1] = Gy0; dd[2] = Gc0;
    dd[3] = Gx1; dd[4] = Gy1; dd[5] = Gc1;
    dd[6] = Gx2; dd[7] = Gy2; dd[8] = Gc2;
    dd[9] = Zx; dd[10] = Zy; dd[11] = Zc;
    // ubkey: zinv of an inside pixel is a convex combo of rz_i → ≤ max rz.
    double ubz = fmax(fmax(rz0, rz1), rz2);
    ((unsigned long long*)dd)[12] =
        ((unsigned long long)__double_as_longlong(ubz) & ~0x7FFull) | 2047ull;
    dd[13] = 0.0; dd[14] = 0.0; dd[15] = 0.0;
    // render UV affine numerators (separate table, not touched by raster)
    int i0 = vti[f * 3 + 0], i1 = vti[f * 3 + 1], i2 = vti[f * 3 + 2];
    double u0d = (double)(2.0f * vt[i0 * 2 + 0] - 1.0f), v0d = (double)(2.0f * vt[i0 * 2 + 1] - 1.0f);
    double u1d = (double)(2.0f * vt[i1 * 2 + 0] - 1.0f), v1d = (double)(2.0f * vt[i1 * 2 + 1] - 1.0f);
    double u2d = (double)(2.0f * vt[i2 * 2 + 0] - 1.0f), v2d = (double)(2.0f * vt[i2 * 2 + 1] - 1.0f);
    double W0x = Gx0 * rz0, W0y = Gy0 * rz0, W0c = Gc0 * rz0;
    double W1x = Gx1 * rz1, W1y = Gy1 * rz1, W1c = Gc1 * rz1;
    double W2x = Gx2 * rz2, W2y = Gy2 * rz2, W2c = Gc2 * rz2;
    double* uv = uvface + (size_t)t * 8;
    uv[0] = (u0d * W0x + u1d * W1x) + u2d * W2x;
    uv[1] = (u0d * W0y + u1d * W1y) + u2d * W2y;
    uv[2] = (u0d * W0c + u1d * W1c) + u2d * W2c;
    uv[3] = (v0d * W0x + v1d * W1x) + v2d * W2x;
    uv[4] = (v0d * W0y + v1d * W1y) + v2d * W2y;
    uv[5] = (v0d * W0c + v1d * W1c) + v2d * W2c;
    uv[6] = 0.0; uv[7] = 0.0;
    // cull record
    float s = (area > 0.0f) ? 1.0f : -1.0f;
    float A0 = -e0y * s, B0 = e0x * s;
    float C0 = s * (float)(e0yd * x1d - e0xd * y1d);
    float A1 = -e1y * s, B1 = e1x * s;
    float C1 = s * (float)(e1yd * x2d - e1xd * y2d);
    float A2 = -e2y * s, B2 = e2x * s;
    float C2 = s * (float)(e2yd * x0d - e2xd * y0d);
    if (!ok) { C0 = -3e30f; C1 = -3e30f; C2 = -3e30f; }
    float xmn = fminf(fminf(X[0], X[1]), X[2]);
    float xmx = fmaxf(fmaxf(X[0], X[1]), X[2]);
    float ymn = fminf(fminf(Y[0], Y[1]), Y[2]);
    float ymx = fmaxf(fmaxf(Y[0], Y[1]), Y[2]);
    float4* cu = cull + (size_t)t * 4;
    cu[0] = make_float4(xmn, ymn, xmx, ymx);
    cu[1] = make_float4(A0, B0, C0, A1);
    cu[2] = make_float4(B1, C1, A2, B2);
    cu[3] = make_float4(C2, 0.0f, 0.0f, 0.0f);
}

// order: per n, bitonic-sort faces by ubkey descending (front-to-back),
// deal sorted ranks round-robin to slices. Sort order is a heuristic only
// (max-merge is permutation-invariant; the break uses per-entry ubkey).
__global__ __launch_bounds__(256) void order(
    const double* __restrict__ dface, unsigned short* __restrict__ perm)
{
    __shared__ unsigned long long sk[FF];
    int n = blockIdx.x, tid = threadIdx.x;
    for (int i = tid; i < FF; i += 256) {
        unsigned long long k =
            ((const unsigned long long*)dface)[((size_t)(n * FF + i)) * 16 + 12];
        sk[i] = (k & ~0x7FFull) | (unsigned long long)i;   // fid in low 11 bits
    }
    __syncthreads();
    for (int k = 2; k <= FF; k <<= 1) {
        for (int j = k >> 1; j > 0; j >>= 1) {
            for (int i = tid; i < FF; i += 256) {
                int ixj = i ^ j;
                if (ixj > i) {
                    unsigned long long a = sk[i], b = sk[ixj];
                    bool up = ((i & k) == 0);
                    if (up ? (a < b) : (a > b)) { sk[i] = b; sk[ixj] = a; }
                }
            }
            __syncthreads();
        }
    }
    for (int i = tid; i < FF; i += 256) {
        unsigned short fid = (unsigned short)(sk[i] & 0x7FFull);
        perm[((size_t)n * SLICES + (i % SLICES)) * FPS + (i / SLICES)] = fid;
    }
}

__device__ __forceinline__ bool edge_keep(float A, float B, float C,
                                          float xlo, float xhi, float ylo, float yhi) {
    float m = A * ((A > 0.0f) ? xhi : xlo) + B * ((B > 0.0f) ? yhi : ylo) + C;
    return m >= -1.0f;   // margin ~0.01 px; f32 eval error << margin
}

// raster: round-4 inner loop (early-z, 44.0 µs) + front-to-back lists +
// conservative wave break. Wave wv owns quadrant wv end-to-end: cull via
// ballot-compaction (order-preserving, no barriers, no LDS atomics), then
// sorted traversal; break when __all(best >= ubkey) — remaining faces
// have ubkey <= head's, and any inside-pixel key <= ubkey, so nothing
// after the break can change any lane's best. Face-key set unchanged →
// selection bit-identical (max-merge is order-independent).
__global__ __launch_bounds__(256) void raster(
    const double* __restrict__ dface, const float4* __restrict__ cull,
    const unsigned short* __restrict__ perm,
    unsigned long long* __restrict__ keybuf)
{
#pragma clang fp contract(fast)
    __shared__ int s_list[4][FPS];
    int nz = blockIdx.z;
    int n = nz / SLICES, slice = nz % SLICES;
    int tx0 = blockIdx.x * 16, ty0 = blockIdx.y * 16;
    int tid = threadIdx.x;
    int lane = tid & 63;
    int wv = tid >> 6;
    int qx0 = tx0 + (wv & 1) * 8;
    int qy0 = ty0 + (wv >> 1) * 8;
    float qxlo = (float)qx0, qxhi = qxlo + 8.0f;
    float qylo = (float)qy0, qyhi = qylo + 8.0f;
    const unsigned short* pm = perm + ((size_t)n * SLICES + slice) * FPS;
    int cnt = 0;
    #pragma unroll
    for (int r2 = 0; r2 < FPS / 64; ++r2) {
        int fid = (int)pm[r2 * 64 + lane];
        const float4* cu = cull + ((size_t)n * FF + fid) * 4;
        float4 bb = cu[0];
        bool keep = false;
        if (bb.x <= qxhi && bb.z >= qxlo && bb.y <= qyhi && bb.w >= qylo) {
            float4 c1 = cu[1], c2 = cu[2], c3 = cu[3];
            keep = edge_keep(c1.x, c1.y, c1.z, qxlo, qxhi, qylo, qyhi) &&
                   edge_keep(c1.w, c2.x, c2.y, qxlo, qxhi, qylo, qyhi) &&
                   edge_keep(c2.z, c2.w, c3.x, qxlo, qxhi, qylo, qyhi);
        }
        unsigned long long mask = __ballot(keep);
        int pos = cnt + (int)__popcll(mask & ((1ull << lane) - 1ull));
        if (keep) s_list[wv][pos] = fid;
        cnt += (int)__popcll(mask);
    }
    double px = (double)(qx0 + (lane & 7)) + 0.5;
    double py = (double)(qy0 + (lane >> 3)) + 0.5;
    unsigned long long best = 0ull;
    const double* gbase = dface + (size_t)n * FF * 16;
    for (int i = 0; i < cnt; ++i) {
        int fid = __builtin_amdgcn_readfirstlane(s_list[wv][i]);
        const double* g = gbase + (size_t)fid * 16;
        unsigned long long ub = ((const unsigned long long*)g)[12];
        if (__all(best >= ub)) break;     // conservative: sorted desc by ub
        double zinv = g[9] * px + (g[10] * py + g[11]);
        unsigned long long key =
            ((unsigned long long)__double_as_longlong(zinv) & ~0x7FFull)
            | (unsigned long long)(2047 - fid);
        bool cand = (zinv > EPSD) && (key > best);
        if (__any(cand)) {
            double b0 = g[0] * px + (g[1] * py + g[2]);
            double b1 = g[3] * px + (g[4] * py + g[5]);
            double b2 = g[6] * px + (g[7] * py + g[8]);
            if (cand && fmin(fmin(b0, b1), b2) >= 0.0) best = key;
        }
    }
    if (best) {
        int x = qx0 + (lane & 7), y = qy0 + (lane >> 3);
        atomicMax(keybuf + ((size_t)n * HH + y) * WW + x, best);
    }
}

// render: affine uv (round-17, proven at floor) + float2-vectorized texel pairs.
__global__ __launch_bounds__(256) void render(
    const double* __restrict__ dface, const double* __restrict__ uvface,
    const unsigned long long* __restrict__ keybuf,
    const float* __restrict__ tex, float* __restrict__ out)
{
    int t = blockIdx.x * blockDim.x + threadIdx.x;
    if (t >= NN * HH * WW) return;
    int n = t / (HH * WW);
    int p = t % (HH * WW);
    int y = p / WW, x = p % WW;
    unsigned long long k = keybuf[t];
    int f = k ? (2047 - (int)(k & 0x7FFull)) : -1;
    size_t o0 = ((size_t)(n * 3 + 0) * HH + y) * WW + x;
    size_t o1 = ((size_t)(n * 3 + 1) * HH + y) * WW + x;
    size_t o2 = ((size_t)(n * 3 + 2) * HH + y) * WW + x;
    if (f < 0) {
        out[o0] = 0.0f; out[o1] = 0.0f; out[o2] = 0.0f;
        return;
    }
    const double* g = dface + ((size_t)n * FF + f) * 16;
    const double* uv = uvface + ((size_t)n * FF + f) * 8;
    double px = (double)x + 0.5, py = (double)y + 0.5;
    double s = g[9] * px + (g[10] * py + g[11]);
    double zq = fmax(s, EPSD);
    double rzq = 1.0 / zq;                     // the ONE f64 division
    double gx = (uv[0] * px + (uv[1] * py + uv[2])) * rzq;
    double gy = (uv[3] * px + (uv[4] * py + uv[5])) * rzq;
    double ix = ((gx + 1.0) * (double)TW - 1.0) * 0.5;
    double iy = ((gy + 1.0) * (double)TH - 1.0) * 0.5;
    double fx0 = floor(ix), fy0 = floor(iy);
    double wx = ix - fx0, wy = iy - fy0;
    int x0 = min(max((int)fx0, 0), TW - 1);
    int x1 = min(max((int)fx0 + 1, 0), TW - 1);
    int y0 = min(max((int)fy0, 0), TH - 1);
    int y1 = min(max((int)fy0 + 1, 0), TH - 1);
    double omwx = 1.0 - wx, omwy = 1.0 - wy;
    bool pair = (x1 == x0 + 1);
    #pragma unroll
    for (int c = 0; c < 3; ++c) {
        const float* tc = tex + ((size_t)n * 3 + c) * TH * TW;
        float g00, g01, g10, g11;
        if (pair) {
            float2 r0 = *(const float2*)(tc + (size_t)y0 * TW + x0);
            float2 r1 = *(const float2*)(tc + (size_t)y1 * TW + x0);
            g00 = r0.x; g01 = r0.y; g10 = r1.x; g11 = r1.y;
        } else {
            g00 = tc[(size_t)y0 * TW + x0];
            g01 = tc[(size_t)y0 * TW + x1];
            g10 = tc[(size_t)y1 * TW + x0];
            g11 = tc[(size_t)y1 * TW + x1];
        }
        double val = ((((double)g00 * omwx) * omwy + ((double)g01 * wx) * omwy)
                      + ((double)g10 * omwx) * wy) + ((double)g11 * wx) * wy;
        size_t oo = (c == 0) ? o0 : ((c == 1) ? o1 : o2);
        out[oo] = (float)val;
    }
}

extern "C" void kernel_launch(void* const* d_in, const int* in_sizes, int n_in,
                              void* d_out, int out_size, void* d_ws, size_t ws_size,
                              hipStream_t stream) {
    const float* v = (const float*)d_in[0];
    const float* tex = (const float*)d_in[1];
    const float* campos = (const float*)d_in[2];
    const float* camrot = (const float*)d_in[3];
    const float* focal = (const float*)d_in[4];
    const float* princpt = (const float*)d_in[5];
    const float* vt = (const float*)d_in[6];
    const int* vi = (const int*)d_in[7];
    const int* vti = (const int*)d_in[8];
    float* out = (float*)d_out;

    char* ws = (char*)d_ws;
    double* dface = (double*)ws;                             // 4096*16*8 = 524288 B
    double* uvface = (double*)(ws + 524288);                 // 4096*8*8 = 262144 B
    float4* cull = (float4*)(ws + 524288 + 262144);          // +262144 B
    unsigned long long* keybuf =
        (unsigned long long*)(ws + 524288 + 262144 + 262144);  // +2359296 B
    unsigned short* perm = (unsigned short*)(ws + 3407872);    // +8192 B

    setup_and_clear<<<dim3(SETUP_BLOCKS + CLEAR_BLOCKS), dim3(256), 0, stream>>>(
        v, campos, camrot, focal, princpt, vi, vt, vti, dface, uvface, cull, keybuf);
    order<<<dim3(NN), dim3(256), 0, stream>>>(dface, perm);
    raster<<<dim3(WW / 16, HH / 16, NN * SLICES), dim3(256), 0, stream>>>(
        dface, cull, perm, keybuf);
    render<<<dim3((NN * HH * WW + 255) / 256), dim3(256), 0, stream>>>(
        dface, uvface, keybuf, tex, out);
}

// Round 9
// 135.811 us; speedup vs baseline: 1.7233x; 1.7233x over previous
//
#include <hip/hip_runtime.h>
#include <math.h>

#pragma clang fp contract(off)

#define NN 2
#define VV 2048
#define FF 2048
#define HH 384
#define WW 384
#define TH 1024
#define TW 1024
#define EPSD 1e-08
#define SLICES 16
#define FPS (FF / SLICES)                          // 128 faces per slice
#define SETUP_BLOCKS ((NN * FF + 255) / 256)       // 16
#define CLEAR_BLOCKS ((NN * HH * WW + 255) / 256)  // 1152

// Separately-rounded fp32 multiply (blocks backend FMA fusion).
__device__ __forceinline__ float mulr(float a, float b) {
    float p = a * b;
    asm("" : "+v"(p));
    return p;
}

// dface: 16 doubles/face (raster hot record, 128 B dense — round-16 layout):
//   [0..8] G (b_i affine), [9..11] Zx,Zy,Zc, [12..15] pad
// uvface: 8 doubles/face (render only): [0..2] Ux,Uy,Uc, [3..5] Vx,Vy,Vc
// cull: float4 x4 (bbox + sign-adjusted raw edge coeffs; !ok → C=-3e30)

__global__ __launch_bounds__(256) void setup_and_clear(
    const float* __restrict__ v, const float* __restrict__ campos,
    const float* __restrict__ camrot, const float* __restrict__ focal,
    const float* __restrict__ princpt, const int* __restrict__ vi,
    const float* __restrict__ vt, const int* __restrict__ vti,
    double* __restrict__ dface, double* __restrict__ uvface,
    float4* __restrict__ cull, unsigned long long* __restrict__ keybuf)
{
#pragma clang fp contract(off)
    if (blockIdx.x >= SETUP_BLOCKS) {
        int idx = (blockIdx.x - SETUP_BLOCKS) * 256 + threadIdx.x;
        if (idx < NN * HH * WW) keybuf[idx] = 0ull;
        return;
    }
    int t = blockIdx.x * blockDim.x + threadIdx.x;
    if (t >= NN * FF) return;
    int n = t / FF, f = t % FF;
    const float* cr = camrot + n * 9;
    const float* cp = campos + n * 3;
    const float* fo = focal + n * 4;
    const float* pp = princpt + n * 2;
    float X[3], Y[3], Z[3];
    for (int k = 0; k < 3; ++k) {
        int vid = vi[f * 3 + k];
        const float* vp = v + ((size_t)n * VV + vid) * 3;
        float d0 = vp[0] - cp[0];
        float d1 = vp[1] - cp[1];
        float d2 = vp[2] - cp[2];
        float c0 = (mulr(cr[0], d0) + mulr(cr[1], d1)) + mulr(cr[2], d2);
        float c1 = (mulr(cr[3], d0) + mulr(cr[4], d1)) + mulr(cr[5], d2);
        float c2 = (mulr(cr[6], d0) + mulr(cr[7], d1)) + mulr(cr[8], d2);
        float u = c0 / c2;
        float w = c1 / c2;
        X[k] = (mulr(fo[0], u) + mulr(fo[1], w)) + pp[0];
        Y[k] = (mulr(fo[2], u) + mulr(fo[3], w)) + pp[1];
        Z[k] = c2;
    }
    float area = mulr(X[1] - X[0], Y[2] - Y[0]) - mulr(Y[1] - Y[0], X[2] - X[0]);
    bool ok = fabsf(area) > 1e-9f;
    float inv = ok ? (1.0f / area) : __builtin_nanf("");
    float e0x = X[2] - X[1], e0y = Y[2] - Y[1];
    float e1x = X[0] - X[2], e1y = Y[0] - Y[2];
    float e2x = X[1] - X[0], e2y = Y[1] - Y[0];
    double invd = (double)inv;
    double e0xd = (double)e0x, e0yd = (double)e0y;
    double e1xd = (double)e1x, e1yd = (double)e1y;
    double e2xd = (double)e2x, e2yd = (double)e2y;
    double x0d = (double)X[0], y0d = (double)Y[0];
    double x1d = (double)X[1], y1d = (double)Y[1];
    double x2d = (double)X[2], y2d = (double)Y[2];
    double rz0 = 1.0 / (double)Z[0];
    double rz1 = 1.0 / (double)Z[1];
    double rz2 = 1.0 / (double)Z[2];
    double Gx0 = -e0yd * invd, Gy0 = e0xd * invd, Gc0 = (e0yd * x1d - e0xd * y1d) * invd;
    double Gx1 = -e1yd * invd, Gy1 = e1xd * invd, Gc1 = (e1yd * x2d - e1xd * y2d) * invd;
    double Gx2 = -e2yd * invd, Gy2 = e2xd * invd, Gc2 = (e2yd * x0d - e2xd * y0d) * invd;
    double Zx = Gx0 * rz0 + Gx1 * rz1 + Gx2 * rz2;
    double Zy = Gy0 * rz0 + Gy1 * rz1 + Gy2 * rz2;
    double Zc = Gc0 * rz0 + Gc1 * rz1 + Gc2 * rz2;
    double* dd = dface + (size_t)t * 16;
    dd[0] = Gx0; dd[1] = Gy0; dd[2] = Gc0;
    dd[3] = Gx1; dd[4] = Gy1; dd[5] = Gc1;
    dd[6] = Gx2; dd[7] = Gy2; dd[8] = Gc2;
    dd[9] = Zx; dd[10] = Zy; dd[11] = Zc;
    dd[12] = 0.0; dd[13] = 0.0; dd[14] = 0.0; dd[15] = 0.0;
    // render UV affine numerators (separate table, not touched by raster)
    int i0 = vti[f * 3 + 0], i1 = vti[f * 3 + 1], i2 = vti[f * 3 + 2];
    double u0d = (double)(2.0f * vt[i0 * 2 + 0] - 1.0f), v0d = (double)(2.0f * vt[i0 * 2 + 1] - 1.0f);
    double u1d = (double)(2.0f * vt[i1 * 2 + 0] - 1.0f), v1d = (double)(2.0f * vt[i1 * 2 + 1] - 1.0f);
    double u2d = (double)(2.0f * vt[i2 * 2 + 0] - 1.0f), v2d = (double)(2.0f * vt[i2 * 2 + 1] - 1.0f);
    double W0x = Gx0 * rz0, W0y = Gy0 * rz0, W0c = Gc0 * rz0;
    double W1x = Gx1 * rz1, W1y = Gy1 * rz1, W1c = Gc1 * rz1;
    double W2x = Gx2 * rz2, W2y = Gy2 * rz2, W2c = Gc2 * rz2;
    double* uv = uvface + (size_t)t * 8;
    uv[0] = (u0d * W0x + u1d * W1x) + u2d * W2x;
    uv[1] = (u0d * W0y + u1d * W1y) + u2d * W2y;
    uv[2] = (u0d * W0c + u1d * W1c) + u2d * W2c;
    uv[3] = (v0d * W0x + v1d * W1x) + v2d * W2x;
    uv[4] = (v0d * W0y + v1d * W1y) + v2d * W2y;
    uv[5] = (v0d * W0c + v1d * W1c) + v2d * W2c;
    uv[6] = 0.0; uv[7] = 0.0;
    // cull record
    float s = (area > 0.0f) ? 1.0f : -1.0f;
    float A0 = -e0y * s, B0 = e0x * s;
    float C0 = s * (float)(e0yd * x1d - e0xd * y1d);
    float A1 = -e1y * s, B1 = e1x * s;
    float C1 = s * (float)(e1yd * x2d - e1xd * y2d);
    float A2 = -e2y * s, B2 = e2x * s;
    float C2 = s * (float)(e2yd * x0d - e2xd * y0d);
    if (!ok) { C0 = -3e30f; C1 = -3e30f; C2 = -3e30f; }
    float xmn = fminf(fminf(X[0], X[1]), X[2]);
    float xmx = fmaxf(fmaxf(X[0], X[1]), X[2]);
    float ymn = fminf(fminf(Y[0], Y[1]), Y[2]);
    float ymx = fmaxf(fmaxf(Y[0], Y[1]), Y[2]);
    float4* cu = cull + (size_t)t * 4;
    cu[0] = make_float4(xmn, ymn, xmx, ymx);
    cu[1] = make_float4(A0, B0, C0, A1);
    cu[2] = make_float4(B1, C1, A2, B2);
    cu[3] = make_float4(C2, 0.0f, 0.0f, 0.0f);
}

// max of edge function over quadrant rect ≥ -1 → may touch quadrant
__device__ __forceinline__ bool edge_keep(float A, float B, float C,
                                          float xlo, float xhi, float ylo, float yhi) {
    float m = A * ((A > 0.0f) ? xhi : xlo) + B * ((B > 0.0f) ? yhi : ylo) + C;
    return m >= -1.0f;   // margin ~0.01 px; f32 eval error << margin
}
// min of edge function over quadrant rect ≥ +1 → face certainly covers
// every pixel center of the quadrant (f32 error << margin 1).
__device__ __forceinline__ bool edge_cover(float A, float B, float C,
                                           float xlo, float xhi, float ylo, float yhi) {
    float m = A * ((A > 0.0f) ? xlo : xhi) + B * ((B > 0.0f) ? ylo : yhi) + C;
    return m >= 1.0f;
}

// raster: round-4 structure (44.0 µs) + per-quadrant hierarchical-z:
//  pass1 (cull): overlap tests as before; for overlapping faces evaluate
//    the f64 zinv plane at the quadrant's 4 rect corners (affine → bounds
//    all pixels). If the face fully COVERS the quadrant (edge_cover ×3,
//    zmn>EPS): atomicMax B[q] with pseudo = (bits(zmn)&~0x7FF)−1 — a key
//    strictly below every key that covering face will write at any lane.
//  pass2: list-build keeps only faces with ubkey=(bits(zmx)&~0x7FF)|2047
//    > B[q] (anything else loses at every lane to the covering face).
//  loop: identical to round 4 but best starts at B[q] — the existing
//    early-z ballot rejects from entry 0. Write if best > B[q].
//  Every filtered/skipped (face,lane) provably loses → selection
//  bit-identical to round 4. NaN (degenerate) faces drop in cull
//  (NaN zmx fails >EPS) — they never passed the in-loop test anyway.
__global__ __launch_bounds__(256) void raster(
    const double* __restrict__ dface, const float4* __restrict__ cull,
    unsigned long long* __restrict__ keybuf)
{
#pragma clang fp contract(fast)
    __shared__ int s_cnt[4];
    __shared__ int s_list[4][FPS];
    __shared__ unsigned long long s_B[4];
    int nz = blockIdx.z;
    int n = nz / SLICES, slice = nz % SLICES;
    int tx0 = blockIdx.x * 16, ty0 = blockIdx.y * 16;
    int tid = threadIdx.x;
    int lane = tid & 63;
    int wv = tid >> 6;
    if (tid < 4) { s_cnt[tid] = 0; s_B[tid] = 0ull; }
    __syncthreads();
    float xlo = (float)tx0, ylo = (float)ty0;
    int f = slice + (tid & 127) * SLICES;         // 128 faces, each by 2 threads
    int qbase = (tid >> 7) * 2;                   // this thread: quadrants qbase, qbase+1
    bool keep0 = false, keep1 = false;
    unsigned long long ub0 = 0ull, ub1 = 0ull;
    {
        const float4* cu = cull + ((size_t)n * FF + f) * 4;
        float4 bb = cu[0];
        if (bb.x <= xlo + 16.0f && bb.z >= xlo && bb.y <= ylo + 16.0f && bb.w >= ylo) {
            float4 c1 = cu[1], c2 = cu[2], c3 = cu[3];
            float qylo = ylo + (float)((qbase >> 1) * 8), qyhi = qylo + 8.0f;
            float xl0 = xlo, xh0 = xlo + 8.0f;          // quadrant qbase   (x-half 0)
            float xl1 = xh0, xh1 = xlo + 16.0f;         // quadrant qbase+1 (x-half 1)
            bool ov0 = bb.x <= xh0 && bb.z >= xl0 && bb.y <= qyhi && bb.w >= qylo &&
                       edge_keep(c1.x, c1.y, c1.z, xl0, xh0, qylo, qyhi) &&
                       edge_keep(c1.w, c2.x, c2.y, xl0, xh0, qylo, qyhi) &&
                       edge_keep(c2.z, c2.w, c3.x, xl0, xh0, qylo, qyhi);
            bool ov1 = bb.x <= xh1 && bb.z >= xl1 && bb.y <= qyhi && bb.w >= qylo &&
                       edge_keep(c1.x, c1.y, c1.z, xl1, xh1, qylo, qyhi) &&
                       edge_keep(c1.w, c2.x, c2.y, xl1, xh1, qylo, qyhi) &&
                       edge_keep(c2.z, c2.w, c3.x, xl1, xh1, qylo, qyhi);
            if (ov0 || ov1) {
                const double* gz = dface + ((size_t)n * FF + f) * 16;
                double Zx = gz[9], Zy = gz[10], Zc = gz[11];
                double qyD = (double)qylo;
                double z00 = Zx * (double)tx0 + (Zy * qyD + Zc);
                double dx8 = Zx * 8.0, dy8 = Zy * 8.0;
                double za0 = z00, za1 = z00 + dx8, za2 = za1 + dx8;
                double zb0 = za0 + dy8, zb1 = za1 + dy8, zb2 = za2 + dy8;
                if (ov0) {
                    double zmn = fmin(fmin(za0, za1), fmin(zb0, zb1));
                    double zmx = fmax(fmax(za0, za1), fmax(zb0, zb1));
                    if (zmx > EPSD) {
                        keep0 = true;
                        ub0 = ((unsigned long long)__double_as_longlong(zmx) & ~0x7FFull) | 2047ull;
                        if (zmn > EPSD &&
                            edge_cover(c1.x, c1.y, c1.z, xl0, xh0, qylo, qyhi) &&
                            edge_cover(c1.w, c2.x, c2.y, xl0, xh0, qylo, qyhi) &&
                            edge_cover(c2.z, c2.w, c3.x, xl0, xh0, qylo, qyhi)) {
                            unsigned long long pz =
                                ((unsigned long long)__double_as_longlong(zmn) & ~0x7FFull) - 1ull;
                            atomicMax(&s_B[qbase], pz);
                        }
                    }
                }
                if (ov1) {
                    double zmn = fmin(fmin(za1, za2), fmin(zb1, zb2));
                    double zmx = fmax(fmax(za1, za2), fmax(zb1, zb2));
                    if (zmx > EPSD) {
                        keep1 = true;
                        ub1 = ((unsigned long long)__double_as_longlong(zmx) & ~0x7FFull) | 2047ull;
                        if (zmn > EPSD &&
                            edge_cover(c1.x, c1.y, c1.z, xl1, xh1, qylo, qyhi) &&
                            edge_cover(c1.w, c2.x, c2.y, xl1, xh1, qylo, qyhi) &&
                            edge_cover(c2.z, c2.w, c3.x, xl1, xh1, qylo, qyhi)) {
                            unsigned long long pz =
                                ((unsigned long long)__double_as_longlong(zmn) & ~0x7FFull) - 1ull;
                            atomicMax(&s_B[qbase + 1], pz);
                        }
                    }
                }
            }
        }
    }
    __syncthreads();   // B[q] final
    if (keep0 && ub0 > s_B[qbase]) {
        int p = atomicAdd(&s_cnt[qbase], 1);
        s_list[qbase][p] = f;
    }
    if (keep1 && ub1 > s_B[qbase + 1]) {
        int p = atomicAdd(&s_cnt[qbase + 1], 1);
        s_list[qbase + 1][p] = f;
    }
    __syncthreads();
    int cnt = s_cnt[wv];
    // Hoist this wave's face list into registers: lane L holds entries L and 64+L.
    int lst0 = s_list[wv][lane];
    int lst1 = s_list[wv][lane + 64];
    int qx0 = tx0 + (wv & 1) * 8;
    int qy0 = ty0 + (wv >> 1) * 8;
    double px = (double)(qx0 + (lane & 7)) + 0.5;
    double py = (double)(qy0 + (lane >> 3)) + 0.5;
    unsigned long long binit = s_B[wv];
    unsigned long long best = binit;
    const double* gbase = dface + (size_t)n * FF * 16;
    for (int i = 0; i < cnt; ++i) {
        int src = (i < 64) ? lst0 : lst1;
        int fid = __builtin_amdgcn_readlane(src, i & 63);  // uniform, no LDS latency
        const double* g = gbase + (size_t)fid * 16;        // uniform → s_load
        double zinv = g[9] * px + (g[10] * py + g[11]);
        unsigned long long key =
            ((unsigned long long)__double_as_longlong(zinv) & ~0x7FFull)
            | (unsigned long long)(2047 - fid);
        bool cand = (zinv > EPSD) && (key > best);
        if (__any(cand)) {
            double b0 = g[0] * px + (g[1] * py + g[2]);
            double b1 = g[3] * px + (g[4] * py + g[5]);
            double b2 = g[6] * px + (g[7] * py + g[8]);
            if (cand && fmin(fmin(b0, b1), b2) >= 0.0) best = key;
        }
    }
    if (best > binit) {
        int x = qx0 + (lane & 7), y = qy0 + (lane >> 3);
        atomicMax(keybuf + ((size_t)n * HH + y) * WW + x, best);
    }
}

// render: affine uv (round-17, proven at floor) + float2-vectorized texel pairs.
__global__ __launch_bounds__(256) void render(
    const double* __restrict__ dface, const double* __restrict__ uvface,
    const unsigned long long* __restrict__ keybuf,
    const float* __restrict__ tex, float* __restrict__ out)
{
    int t = blockIdx.x * blockDim.x + threadIdx.x;
    if (t >= NN * HH * WW) return;
    int n = t / (HH * WW);
    int p = t % (HH * WW);
    int y = p / WW, x = p % WW;
    unsigned long long k = keybuf[t];
    int f = k ? (2047 - (int)(k & 0x7FFull)) : -1;
    size_t o0 = ((size_t)(n * 3 + 0) * HH + y) * WW + x;
    size_t o1 = ((size_t)(n * 3 + 1) * HH + y) * WW + x;
    size_t o2 = ((size_t)(n * 3 + 2) * HH + y) * WW + x;
    if (f < 0) {
        out[o0] = 0.0f; out[o1] = 0.0f; out[o2] = 0.0f;
        return;
    }
    const double* g = dface + ((size_t)n * FF + f) * 16;
    const double* uv = uvface + ((size_t)n * FF + f) * 8;
    double px = (double)x + 0.5, py = (double)y + 0.5;
    double s = g[9] * px + (g[10] * py + g[11]);
    double zq = fmax(s, EPSD);
    double rzq = 1.0 / zq;                     // the ONE f64 division
    double gx = (uv[0] * px + (uv[1] * py + uv[2])) * rzq;
    double gy = (uv[3] * px + (uv[4] * py + uv[5])) * rzq;
    double ix = ((gx + 1.0) * (double)TW - 1.0) * 0.5;
    double iy = ((gy + 1.0) * (double)TH - 1.0) * 0.5;
    double fx0 = floor(ix), fy0 = floor(iy);
    double wx = ix - fx0, wy = iy - fy0;
    int x0 = min(max((int)fx0, 0), TW - 1);
    int x1 = min(max((int)fx0 + 1, 0), TW - 1);
    int y0 = min(max((int)fy0, 0), TH - 1);
    int y1 = min(max((int)fy0 + 1, 0), TH - 1);
    double omwx = 1.0 - wx, omwy = 1.0 - wy;
    bool pair = (x1 == x0 + 1);
    #pragma unroll
    for (int c = 0; c < 3; ++c) {
        const float* tc = tex + ((size_t)n * 3 + c) * TH * TW;
        float g00, g01, g10, g11;
        if (pair) {
            float2 r0 = *(const float2*)(tc + (size_t)y0 * TW + x0);
            float2 r1 = *(const float2*)(tc + (size_t)y1 * TW + x0);
            g00 = r0.x; g01 = r0.y; g10 = r1.x; g11 = r1.y;
        } else {
            g00 = tc[(size_t)y0 * TW + x0];
            g01 = tc[(size_t)y0 * TW + x1];
            g10 = tc[(size_t)y1 * TW + x0];
            g11 = tc[(size_t)y1 * TW + x1];
        }
        double val = ((((double)g00 * omwx) * omwy + ((double)g01 * wx) * omwy)
                      + ((double)g10 * omwx) * wy) + ((double)g11 * wx) * wy;
        size_t oo = (c == 0) ? o0 : ((c == 1) ? o1 : o2);
        out[oo] = (float)val;
    }
}

extern "C" void kernel_launch(void* const* d_in, const int* in_sizes, int n_in,
                              void* d_out, int out_size, void* d_ws, size_t ws_size,
                              hipStream_t stream) {
    const float* v = (const float*)d_in[0];
    const float* tex = (const float*)d_in[1];
    const float* campos = (const float*)d_in[2];
    const float* camrot = (const float*)d_in[3];
    const float* focal = (const float*)d_in[4];
    const float* princpt = (const float*)d_in[5];
    const float* vt = (const float*)d_in[6];
    const int* vi = (const int*)d_in[7];
    const int* vti = (const int*)d_in[8];
    float* out = (float*)d_out;

    char* ws = (char*)d_ws;
    double* dface = (double*)ws;                             // 4096*16*8 = 524288 B
    double* uvface = (double*)(ws + 524288);                 // 4096*8*8 = 262144 B
    float4* cull = (float4*)(ws + 524288 + 262144);          // +262144 B
    unsigned long long* keybuf =
        (unsigned long long*)(ws + 524288 + 262144 + 262144);  // +2359296 B

    setup_and_clear<<<dim3(SETUP_BLOCKS + CLEAR_BLOCKS), dim3(256), 0, stream>>>(
        v, campos, camrot, focal, princpt, vi, vt, vti, dface, uvface, cull, keybuf);
    raster<<<dim3(WW / 16, HH / 16, NN * SLICES), dim3(256), 0, stream>>>(
        dface, cull, keybuf);
    render<<<dim3((NN * HH * WW + 255) / 256), dim3(256), 0, stream>>>(
        dface, uvface, keybuf, tex, out);
}

// Round 10
// 133.638 us; speedup vs baseline: 1.7513x; 1.0163x over previous
//
#include <hip/hip_runtime.h>
#include <math.h>

#pragma clang fp contract(off)

#define NN 2
#define VV 2048
#define FF 2048
#define HH 384
#define WW 384
#define TH 1024
#define TW 1024
#define EPSD 1e-08
#define SLICES 8
#define FPS (FF / SLICES)                          // 256 faces per slice
#define SETUP_BLOCKS ((NN * FF + 255) / 256)       // 16
#define CLEAR_BLOCKS ((NN * HH * WW + 255) / 256)  // 1152

// Separately-rounded fp32 multiply (blocks backend FMA fusion).
__device__ __forceinline__ float mulr(float a, float b) {
    float p = a * b;
    asm("" : "+v"(p));
    return p;
}

// dface: 16 doubles/face (raster hot record, 128 B dense — round-16 layout):
//   [0..8] G (b_i affine), [9..11] Zx,Zy,Zc, [12..15] pad
// uvface: 8 doubles/face (render only): [0..2] Ux,Uy,Uc, [3..5] Vx,Vy,Vc
// cull: float4 x4 (bbox + sign-adjusted raw edge coeffs; !ok → C=-3e30)

__global__ __launch_bounds__(256) void setup_and_clear(
    const float* __restrict__ v, const float* __restrict__ campos,
    const float* __restrict__ camrot, const float* __restrict__ focal,
    const float* __restrict__ princpt, const int* __restrict__ vi,
    const float* __restrict__ vt, const int* __restrict__ vti,
    double* __restrict__ dface, double* __restrict__ uvface,
    float4* __restrict__ cull, unsigned long long* __restrict__ keybuf)
{
#pragma clang fp contract(off)
    if (blockIdx.x >= SETUP_BLOCKS) {
        int idx = (blockIdx.x - SETUP_BLOCKS) * 256 + threadIdx.x;
        if (idx < NN * HH * WW) keybuf[idx] = 0ull;
        return;
    }
    int t = blockIdx.x * blockDim.x + threadIdx.x;
    if (t >= NN * FF) return;
    int n = t / FF, f = t % FF;
    const float* cr = camrot + n * 9;
    const float* cp = campos + n * 3;
    const float* fo = focal + n * 4;
    const float* pp = princpt + n * 2;
    float X[3], Y[3], Z[3];
    for (int k = 0; k < 3; ++k) {
        int vid = vi[f * 3 + k];
        const float* vp = v + ((size_t)n * VV + vid) * 3;
        float d0 = vp[0] - cp[0];
        float d1 = vp[1] - cp[1];
        float d2 = vp[2] - cp[2];
        float c0 = (mulr(cr[0], d0) + mulr(cr[1], d1)) + mulr(cr[2], d2);
        float c1 = (mulr(cr[3], d0) + mulr(cr[4], d1)) + mulr(cr[5], d2);
        float c2 = (mulr(cr[6], d0) + mulr(cr[7], d1)) + mulr(cr[8], d2);
        float u = c0 / c2;
        float w = c1 / c2;
        X[k] = (mulr(fo[0], u) + mulr(fo[1], w)) + pp[0];
        Y[k] = (mulr(fo[2], u) + mulr(fo[3], w)) + pp[1];
        Z[k] = c2;
    }
    float area = mulr(X[1] - X[0], Y[2] - Y[0]) - mulr(Y[1] - Y[0], X[2] - X[0]);
    bool ok = fabsf(area) > 1e-9f;
    float inv = ok ? (1.0f / area) : __builtin_nanf("");
    float e0x = X[2] - X[1], e0y = Y[2] - Y[1];
    float e1x = X[0] - X[2], e1y = Y[0] - Y[2];
    float e2x = X[1] - X[0], e2y = Y[1] - Y[0];
    double invd = (double)inv;
    double e0xd = (double)e0x, e0yd = (double)e0y;
    double e1xd = (double)e1x, e1yd = (double)e1y;
    double e2xd = (double)e2x, e2yd = (double)e2y;
    double x0d = (double)X[0], y0d = (double)Y[0];
    double x1d = (double)X[1], y1d = (double)Y[1];
    double x2d = (double)X[2], y2d = (double)Y[2];
    double rz0 = 1.0 / (double)Z[0];
    double rz1 = 1.0 / (double)Z[1];
    double rz2 = 1.0 / (double)Z[2];
    double Gx0 = -e0yd * invd, Gy0 = e0xd * invd, Gc0 = (e0yd * x1d - e0xd * y1d) * invd;
    double Gx1 = -e1yd * invd, Gy1 = e1xd * invd, Gc1 = (e1yd * x2d - e1xd * y2d) * invd;
    double Gx2 = -e2yd * invd, Gy2 = e2xd * invd, Gc2 = (e2yd * x0d - e2xd * y0d) * invd;
    double Zx = Gx0 * rz0 + Gx1 * rz1 + Gx2 * rz2;
    double Zy = Gy0 * rz0 + Gy1 * rz1 + Gy2 * rz2;
    double Zc = Gc0 * rz0 + Gc1 * rz1 + Gc2 * rz2;
    double* dd = dface + (size_t)t * 16;
    dd[0] = Gx0; dd[1] = Gy0; dd[2] = Gc0;
    dd[3] = Gx1; dd[4] = Gy1; dd[5] = Gc1;
    dd[6] = Gx2; dd[7] = Gy2; dd[8] = Gc2;
    dd[9] = Zx; dd[10] = Zy; dd[11] = Zc;
    dd[12] = 0.0; dd[13] = 0.0; dd[14] = 0.0; dd[15] = 0.0;
    // render UV affine numerators (separate table, not touched by raster)
    int i0 = vti[f * 3 + 0], i1 = vti[f * 3 + 1], i2 = vti[f * 3 + 2];
    double u0d = (double)(2.0f * vt[i0 * 2 + 0] - 1.0f), v0d = (double)(2.0f * vt[i0 * 2 + 1] - 1.0f);
    double u1d = (double)(2.0f * vt[i1 * 2 + 0] - 1.0f), v1d = (double)(2.0f * vt[i1 * 2 + 1] - 1.0f);
    double u2d = (double)(2.0f * vt[i2 * 2 + 0] - 1.0f), v2d = (double)(2.0f * vt[i2 * 2 + 1] - 1.0f);
    double W0x = Gx0 * rz0, W0y = Gy0 * rz0, W0c = Gc0 * rz0;
    double W1x = Gx1 * rz1, W1y = Gy1 * rz1, W1c = Gc1 * rz1;
    double W2x = Gx2 * rz2, W2y = Gy2 * rz2, W2c = Gc2 * rz2;
    double* uv = uvface + (size_t)t * 8;
    uv[0] = (u0d * W0x + u1d * W1x) + u2d * W2x;
    uv[1] = (u0d * W0y + u1d * W1y) + u2d * W2y;
    uv[2] = (u0d * W0c + u1d * W1c) + u2d * W2c;
    uv[3] = (v0d * W0x + v1d * W1x) + v2d * W2x;
    uv[4] = (v0d * W0y + v1d * W1y) + v2d * W2y;
    uv[5] = (v0d * W0c + v1d * W1c) + v2d * W2c;
    uv[6] = 0.0; uv[7] = 0.0;
    // cull record
    float s = (area > 0.0f) ? 1.0f : -1.0f;
    float A0 = -e0y * s, B0 = e0x * s;
    float C0 = s * (float)(e0yd * x1d - e0xd * y1d);
    float A1 = -e1y * s, B1 = e1x * s;
    float C1 = s * (float)(e1yd * x2d - e1xd * y2d);
    float A2 = -e2y * s, B2 = e2x * s;
    float C2 = s * (float)(e2yd * x0d - e2xd * y0d);
    if (!ok) { C0 = -3e30f; C1 = -3e30f; C2 = -3e30f; }
    float xmn = fminf(fminf(X[0], X[1]), X[2]);
    float xmx = fmaxf(fmaxf(X[0], X[1]), X[2]);
    float ymn = fminf(fminf(Y[0], Y[1]), Y[2]);
    float ymx = fmaxf(fmaxf(Y[0], Y[1]), Y[2]);
    float4* cu = cull + (size_t)t * 4;
    cu[0] = make_float4(xmn, ymn, xmx, ymx);
    cu[1] = make_float4(A0, B0, C0, A1);
    cu[2] = make_float4(B1, C1, A2, B2);
    cu[3] = make_float4(C2, 0.0f, 0.0f, 0.0f);
}

// max of edge function over quadrant rect ≥ -1 → may touch quadrant
__device__ __forceinline__ bool edge_keep(float A, float B, float C,
                                          float xlo, float xhi, float ylo, float yhi) {
    float m = A * ((A > 0.0f) ? xhi : xlo) + B * ((B > 0.0f) ? yhi : ylo) + C;
    return m >= -1.0f;   // margin ~0.01 px; f32 eval error << margin
}
// min of edge function over quadrant rect ≥ +1 → face certainly covers
// every pixel center of the quadrant (f32 error << margin 1).
__device__ __forceinline__ bool edge_cover(float A, float B, float C,
                                           float xlo, float xhi, float ylo, float yhi) {
    float m = A * ((A > 0.0f) ? xlo : xhi) + B * ((B > 0.0f) ? ylo : yhi) + C;
    return m >= 1.0f;
}

// raster: round-9 hierarchical-z structure (proven −7 µs) with SLICES 8:
// each block culls 256 faces (2 statically-unrolled halves per thread) →
// larger covering-face pool → tighter B[q] → stronger list filter; one
// 256-face pass replaces two 128-face passes (fewer per-pixel takes);
// keybuf atomic rounds halve. Serial loop and all f64 decision math
// byte-identical to round 9 → selection unchanged.
__global__ __launch_bounds__(256) void raster(
    const double* __restrict__ dface, const float4* __restrict__ cull,
    unsigned long long* __restrict__ keybuf)
{
#pragma clang fp contract(fast)
    __shared__ int s_cnt[4];
    __shared__ int s_list[4][FPS];
    __shared__ unsigned long long s_B[4];
    int nz = blockIdx.z;
    int n = nz / SLICES, slice = nz % SLICES;
    int tx0 = blockIdx.x * 16, ty0 = blockIdx.y * 16;
    int tid = threadIdx.x;
    int lane = tid & 63;
    int wv = tid >> 6;
    if (tid < 4) { s_cnt[tid] = 0; s_B[tid] = 0ull; }
    __syncthreads();
    float xlo = (float)tx0, ylo = (float)ty0;
    int qbase = (tid >> 7) * 2;                   // this thread: quadrants qbase, qbase+1
    bool keep0[2] = {false, false}, keep1[2] = {false, false};
    unsigned long long ub0[2] = {0ull, 0ull}, ub1[2] = {0ull, 0ull};
    int fh[2];
    #pragma unroll
    for (int h = 0; h < 2; ++h) {
        int f = slice + ((tid & 127) + h * 128) * SLICES;
        fh[h] = f;
        const float4* cu = cull + ((size_t)n * FF + f) * 4;
        float4 bb = cu[0];
        if (bb.x <= xlo + 16.0f && bb.z >= xlo && bb.y <= ylo + 16.0f && bb.w >= ylo) {
            float4 c1 = cu[1], c2 = cu[2], c3 = cu[3];
            float qylo = ylo + (float)((qbase >> 1) * 8), qyhi = qylo + 8.0f;
            float xl0 = xlo, xh0 = xlo + 8.0f;          // quadrant qbase   (x-half 0)
            float xl1 = xh0, xh1 = xlo + 16.0f;         // quadrant qbase+1 (x-half 1)
            bool ov0 = bb.x <= xh0 && bb.z >= xl0 && bb.y <= qyhi && bb.w >= qylo &&
                       edge_keep(c1.x, c1.y, c1.z, xl0, xh0, qylo, qyhi) &&
                       edge_keep(c1.w, c2.x, c2.y, xl0, xh0, qylo, qyhi) &&
                       edge_keep(c2.z, c2.w, c3.x, xl0, xh0, qylo, qyhi);
            bool ov1 = bb.x <= xh1 && bb.z >= xl1 && bb.y <= qyhi && bb.w >= qylo &&
                       edge_keep(c1.x, c1.y, c1.z, xl1, xh1, qylo, qyhi) &&
                       edge_keep(c1.w, c2.x, c2.y, xl1, xh1, qylo, qyhi) &&
                       edge_keep(c2.z, c2.w, c3.x, xl1, xh1, qylo, qyhi);
            if (ov0 || ov1) {
                const double* gz = dface + ((size_t)n * FF + f) * 16;
                double Zx = gz[9], Zy = gz[10], Zc = gz[11];
                double qyD = (double)qylo;
                double z00 = Zx * (double)tx0 + (Zy * qyD + Zc);
                double dx8 = Zx * 8.0, dy8 = Zy * 8.0;
                double za0 = z00, za1 = z00 + dx8, za2 = za1 + dx8;
                double zb0 = za0 + dy8, zb1 = za1 + dy8, zb2 = za2 + dy8;
                if (ov0) {
                    double zmn = fmin(fmin(za0, za1), fmin(zb0, zb1));
                    double zmx = fmax(fmax(za0, za1), fmax(zb0, zb1));
                    if (zmx > EPSD) {
                        keep0[h] = true;
                        ub0[h] = ((unsigned long long)__double_as_longlong(zmx) & ~0x7FFull) | 2047ull;
                        if (zmn > EPSD &&
                            edge_cover(c1.x, c1.y, c1.z, xl0, xh0, qylo, qyhi) &&
                            edge_cover(c1.w, c2.x, c2.y, xl0, xh0, qylo, qyhi) &&
                            edge_cover(c2.z, c2.w, c3.x, xl0, xh0, qylo, qyhi)) {
                            unsigned long long pz =
                                ((unsigned long long)__double_as_longlong(zmn) & ~0x7FFull) - 1ull;
                            atomicMax(&s_B[qbase], pz);
                        }
                    }
                }
                if (ov1) {
                    double zmn = fmin(fmin(za1, za2), fmin(zb1, zb2));
                    double zmx = fmax(fmax(za1, za2), fmax(zb1, zb2));
                    if (zmx > EPSD) {
                        keep1[h] = true;
                        ub1[h] = ((unsigned long long)__double_as_longlong(zmx) & ~0x7FFull) | 2047ull;
                        if (zmn > EPSD &&
                            edge_cover(c1.x, c1.y, c1.z, xl1, xh1, qylo, qyhi) &&
                            edge_cover(c1.w, c2.x, c2.y, xl1, xh1, qylo, qyhi) &&
                            edge_cover(c2.z, c2.w, c3.x, xl1, xh1, qylo, qyhi)) {
                            unsigned long long pz =
                                ((unsigned long long)__double_as_longlong(zmn) & ~0x7FFull) - 1ull;
                            atomicMax(&s_B[qbase + 1], pz);
                        }
                    }
                }
            }
        }
    }
    __syncthreads();   // B[q] final
    #pragma unroll
    for (int h = 0; h < 2; ++h) {
        if (keep0[h] && ub0[h] > s_B[qbase]) {
            int p = atomicAdd(&s_cnt[qbase], 1);
            s_list[qbase][p] = fh[h];
        }
        if (keep1[h] && ub1[h] > s_B[qbase + 1]) {
            int p = atomicAdd(&s_cnt[qbase + 1], 1);
            s_list[qbase + 1][p] = fh[h];
        }
    }
    __syncthreads();
    int cnt = s_cnt[wv];
    // Hoist this wave's face list into registers: lane L holds entries
    // L, 64+L, 128+L, 192+L (covers the full FPS=256 worst case).
    int lst0 = s_list[wv][lane];
    int lst1 = s_list[wv][lane + 64];
    int lst2 = s_list[wv][lane + 128];
    int lst3 = s_list[wv][lane + 192];
    int qx0 = tx0 + (wv & 1) * 8;
    int qy0 = ty0 + (wv >> 1) * 8;
    double px = (double)(qx0 + (lane & 7)) + 0.5;
    double py = (double)(qy0 + (lane >> 3)) + 0.5;
    unsigned long long binit = s_B[wv];
    unsigned long long best = binit;
    const double* gbase = dface + (size_t)n * FF * 16;
    for (int i = 0; i < cnt; ++i) {
        int src = (i < 128) ? ((i < 64) ? lst0 : lst1)
                            : ((i < 192) ? lst2 : lst3);
        int fid = __builtin_amdgcn_readlane(src, i & 63);  // uniform, no LDS latency
        const double* g = gbase + (size_t)fid * 16;        // uniform → s_load
        double zinv = g[9] * px + (g[10] * py + g[11]);
        unsigned long long key =
            ((unsigned long long)__double_as_longlong(zinv) & ~0x7FFull)
            | (unsigned long long)(2047 - fid);
        bool cand = (zinv > EPSD) && (key > best);
        if (__any(cand)) {
            double b0 = g[0] * px + (g[1] * py + g[2]);
            double b1 = g[3] * px + (g[4] * py + g[5]);
            double b2 = g[6] * px + (g[7] * py + g[8]);
            if (cand && fmin(fmin(b0, b1), b2) >= 0.0) best = key;
        }
    }
    if (best > binit) {
        int x = qx0 + (lane & 7), y = qy0 + (lane >> 3);
        atomicMax(keybuf + ((size_t)n * HH + y) * WW + x, best);
    }
}

// render: affine uv (round-17, proven at floor) + float2-vectorized texel pairs.
__global__ __launch_bounds__(256) void render(
    const double* __restrict__ dface, const double* __restrict__ uvface,
    const unsigned long long* __restrict__ keybuf,
    const float* __restrict__ tex, float* __restrict__ out)
{
    int t = blockIdx.x * blockDim.x + threadIdx.x;
    if (t >= NN * HH * WW) return;
    int n = t / (HH * WW);
    int p = t % (HH * WW);
    int y = p / WW, x = p % WW;
    unsigned long long k = keybuf[t];
    int f = k ? (2047 - (int)(k & 0x7FFull)) : -1;
    size_t o0 = ((size_t)(n * 3 + 0) * HH + y) * WW + x;
    size_t o1 = ((size_t)(n * 3 + 1) * HH + y) * WW + x;
    size_t o2 = ((size_t)(n * 3 + 2) * HH + y) * WW + x;
    if (f < 0) {
        out[o0] = 0.0f; out[o1] = 0.0f; out[o2] = 0.0f;
        return;
    }
    const double* g = dface + ((size_t)n * FF + f) * 16;
    const double* uv = uvface + ((size_t)n * FF + f) * 8;
    double px = (double)x + 0.5, py = (double)y + 0.5;
    double s = g[9] * px + (g[10] * py + g[11]);
    double zq = fmax(s, EPSD);
    double rzq = 1.0 / zq;                     // the ONE f64 division
    double gx = (uv[0] * px + (uv[1] * py + uv[2])) * rzq;
    double gy = (uv[3] * px + (uv[4] * py + uv[5])) * rzq;
    double ix = ((gx + 1.0) * (double)TW - 1.0) * 0.5;
    double iy = ((gy + 1.0) * (double)TH - 1.0) * 0.5;
    double fx0 = floor(ix), fy0 = floor(iy);
    double wx = ix - fx0, wy = iy - fy0;
    int x0 = min(max((int)fx0, 0), TW - 1);
    int x1 = min(max((int)fx0 + 1, 0), TW - 1);
    int y0 = min(max((int)fy0, 0), TH - 1);
    int y1 = min(max((int)fy0 + 1, 0), TH - 1);
    double omwx = 1.0 - wx, omwy = 1.0 - wy;
    bool pair = (x1 == x0 + 1);
    #pragma unroll
    for (int c = 0; c < 3; ++c) {
        const float* tc = tex + ((size_t)n * 3 + c) * TH * TW;
        float g00, g01, g10, g11;
        if (pair) {
            float2 r0 = *(const float2*)(tc + (size_t)y0 * TW + x0);
            float2 r1 = *(const float2*)(tc + (size_t)y1 * TW + x0);
            g00 = r0.x; g01 = r0.y; g10 = r1.x; g11 = r1.y;
        } else {
            g00 = tc[(size_t)y0 * TW + x0];
            g01 = tc[(size_t)y0 * TW + x1];
            g10 = tc[(size_t)y1 * TW + x0];
            g11 = tc[(size_t)y1 * TW + x1];
        }
        double val = ((((double)g00 * omwx) * omwy + ((double)g01 * wx) * omwy)
                      + ((double)g10 * omwx) * wy) + ((double)g11 * wx) * wy;
        size_t oo = (c == 0) ? o0 : ((c == 1) ? o1 : o2);
        out[oo] = (float)val;
    }
}

extern "C" void kernel_launch(void* const* d_in, const int* in_sizes, int n_in,
                              void* d_out, int out_size, void* d_ws, size_t ws_size,
                              hipStream_t stream) {
    const float* v = (const float*)d_in[0];
    const float* tex = (const float*)d_in[1];
    const float* campos = (const float*)d_in[2];
    const float* camrot = (const float*)d_in[3];
    const float* focal = (const float*)d_in[4];
    const float* princpt = (const float*)d_in[5];
    const float* vt = (const float*)d_in[6];
    const int* vi = (const int*)d_in[7];
    const int* vti = (const int*)d_in[8];
    float* out = (float*)d_out;

    char* ws = (char*)d_ws;
    double* dface = (double*)ws;                             // 4096*16*8 = 524288 B
    double* uvface = (double*)(ws + 524288);                 // 4096*8*8 = 262144 B
    float4* cull = (float4*)(ws + 524288 + 262144);          // +262144 B
    unsigned long long* keybuf =
        (unsigned long long*)(ws + 524288 + 262144 + 262144);  // +2359296 B

    setup_and_clear<<<dim3(SETUP_BLOCKS + CLEAR_BLOCKS), dim3(256), 0, stream>>>(
        v, campos, camrot, focal, princpt, vi, vt, vti, dface, uvface, cull, keybuf);
    raster<<<dim3(WW / 16, HH / 16, NN * SLICES), dim3(256), 0, stream>>>(
        dface, cull, keybuf);
    render<<<dim3((NN * HH * WW + 255) / 256), dim3(256), 0, stream>>>(
        dface, uvface, keybuf, tex, out);
}